// Round 7
// baseline (520.560 us; speedup 1.0000x reference)
//
#include <hip/hip_runtime.h>
#include <math.h>

// Problem constants: N=500000, NFEAT=64, K=8, HK=64
constexpr int NS    = 500000;
constexpr int NF    = 64;
constexpr int KG    = 8;
constexpr int HKC   = 64;
constexpr int NCELL = KG * HKC;            // 512 histogram cells
constexpr int RPW   = 32;                  // rows per wave (NS % 32 == 0)
constexpr int RPB   = 128;                 // rows per block (4 waves)
constexpr int NBLK  = (NS + RPB - 1) / RPB;   // 3907
constexpr int NSLOT = 1954;                // partial slots (2 blocks share 1)

typedef __attribute__((ext_vector_type(8))) _Float16 half8;
typedef __attribute__((ext_vector_type(4))) float f32x4;

// xor-16 within 32-lane halves: ds_swizzle BitMode offset 0x401F
__device__ __forceinline__ float swz16_f(float v) {
    return __int_as_float(__builtin_amdgcn_ds_swizzle(__float_as_int(v), 0x401F));
}
__device__ __forceinline__ int swz16_i(int v) {
    return __builtin_amdgcn_ds_swizzle(v, 0x401F);
}

// Kernel 1: w = exp(z) split to fp16 hi/lo; zero A and the partial buffer.
__global__ void prep_kernel(const float* __restrict__ z,
                            _Float16* __restrict__ w_hi,
                            _Float16* __restrict__ w_lo,
                            float* __restrict__ A,
                            float4* __restrict__ pzero, int n4) {
    int i = blockIdx.x * blockDim.x + threadIdx.x;
    if (i < KG * HKC * NF) {
        float w = expf(z[i]);
        _Float16 h = (_Float16)w;           // RNE
        w_hi[i] = h;
        w_lo[i] = (_Float16)(w - (float)h); // residual: ~2^-22 total pair error
    }
    if (i < NCELL) A[i] = 0.0f;
    for (int j = i; j < n4; j += gridDim.x * blockDim.x)
        pzero[j] = (float4){0.f, 0.f, 0.f, 0.f};
}

// Main kernel: one wave = 32 rows (2 MFMA tiles) x all 512 w-cols.
// R6 post-mortem: both pipes ~20%, occupancy 21% -> TLP-starved. This round:
// half the rows/wave (2x waves, half per-wave serial chain), registers capped
// via __launch_bounds__(256,4) targeting 4-5 waves/SIMD resident.
// Transposed-C orientation (mfma(W,X)): lane holds 16 w-cols of ONE x-row ->
// in-lane argmax. 3-pass split (hh,lh,hl): no dependent MFMA triplets.
template <bool PRIV>
__global__ __launch_bounds__(256, 4) void monn_mfma_kernel(
    const float* __restrict__ x,
    const _Float16* __restrict__ w_hi,
    const _Float16* __restrict__ w_lo,
    const float* __restrict__ t,
    float* __restrict__ y,
    float* __restrict__ dest) {   // PRIV ? partial buffer : global A

    __shared__ unsigned lhist[NCELL];
    if (PRIV) {
        for (int i = threadIdx.x; i < NCELL; i += 256) lhist[i] = 0u;
        __syncthreads();
    }

    const int lane = threadIdx.x & 63;
    const long base = (long)blockIdx.x * RPB + (threadIdx.x >> 6) * RPW;
    const int m  = lane & 15;
    const int q  = lane >> 4;
    const int q4 = q * 4;
    const int a32 = ((lane ^ 32) << 2);   // ds_bpermute byte-addr for xor-32

    if (base < NS) {   // wave-uniform predicate; NS%32==0 -> active waves are full
        // --- Load 32 x rows, split to fp16 hi/lo (B-operand layout:
        //     B[k=q*8+j][n=lane&15], same addressing as A layout) ---
        half8 Xh[2][2], Xl[2][2];
#pragma unroll
        for (int rt = 0; rt < 2; ++rt) {
            const float* xp = x + (base + rt * 16 + m) * NF;
#pragma unroll
            for (int s = 0; s < 2; ++s) {
                const int k0 = s * 32 + q * 8;
                const float4 v0 = *reinterpret_cast<const float4*>(xp + k0);
                const float4 v1 = *reinterpret_cast<const float4*>(xp + k0 + 4);
                const float f[8] = {v0.x, v0.y, v0.z, v0.w, v1.x, v1.y, v1.z, v1.w};
#pragma unroll
                for (int j = 0; j < 8; ++j) {
                    _Float16 h = (_Float16)f[j];
                    Xh[rt][s][j] = h;
                    Xl[rt][s][j] = (_Float16)(f[j] - (float)h);
                }
            }
        }

        float ymin[2] = {INFINITY, INFINITY};
        int   code[2] = {0, 0};

#pragma unroll 2
        for (int g = 0; g < KG; ++g) {
            // bias folded into acc init: lane's w-cols are c*16 + q4 + j
            f32x4 acc[4][2];   // [c (w tile)][rt (x tile)]
#pragma unroll
            for (int c = 0; c < 4; ++c) {
                const float4 tv = *reinterpret_cast<const float4*>(t + g * HKC + c * 16 + q4);
                const f32x4 tin = (f32x4){tv.x, tv.y, tv.z, tv.w};
                acc[c][0] = tin;
                acc[c][1] = tin;
            }

#pragma unroll
            for (int s = 0; s < 2; ++s) {
                // batch 8 w loads (A-operand layout A[m=lane&15][k=q*8+j])
                half8 Wh[4], Wl[4];
#pragma unroll
                for (int c = 0; c < 4; ++c) {
                    const size_t off = (size_t)(g * HKC + c * 16 + m) * NF + s * 32 + q * 8;
                    Wh[c] = *reinterpret_cast<const half8*>(w_hi + off);
                    Wl[c] = *reinterpret_cast<const half8*>(w_lo + off);
                }
                // pass 1: wh*xh — 8 independent MFMAs
#pragma unroll
                for (int c = 0; c < 4; ++c)
#pragma unroll
                    for (int rt = 0; rt < 2; ++rt)
                        acc[c][rt] = __builtin_amdgcn_mfma_f32_16x16x32_f16(Wh[c], Xh[rt][s], acc[c][rt], 0, 0, 0);
                // pass 2: wl*xh
#pragma unroll
                for (int c = 0; c < 4; ++c)
#pragma unroll
                    for (int rt = 0; rt < 2; ++rt)
                        acc[c][rt] = __builtin_amdgcn_mfma_f32_16x16x32_f16(Wl[c], Xh[rt][s], acc[c][rt], 0, 0, 0);
                // pass 3: wh*xl
#pragma unroll
                for (int c = 0; c < 4; ++c)
#pragma unroll
                    for (int rt = 0; rt < 2; ++rt)
                        acc[c][rt] = __builtin_amdgcn_mfma_f32_16x16x32_f16(Wh[c], Xl[rt][s], acc[c][rt], 0, 0, 0);
            }

            // --- epilogue: per x-row argmax over this group's 64 w-cols ---
#pragma unroll
            for (int rt = 0; rt < 2; ++rt) {
                float t01 = fmaxf(acc[0][rt][0], acc[0][rt][1]);
                float t23 = fmaxf(acc[0][rt][2], acc[0][rt][3]);
                float t45 = fmaxf(acc[1][rt][0], acc[1][rt][1]);
                float t67 = fmaxf(acc[1][rt][2], acc[1][rt][3]);
                float t89 = fmaxf(acc[2][rt][0], acc[2][rt][1]);
                float tab = fmaxf(acc[2][rt][2], acc[2][rt][3]);
                float tcd = fmaxf(acc[3][rt][0], acc[3][rt][1]);
                float tef = fmaxf(acc[3][rt][2], acc[3][rt][3]);
                float v = fmaxf(fmaxf(fmaxf(t01, t23), fmaxf(t45, t67)),
                                fmaxf(fmaxf(t89, tab), fmaxf(tcd, tef)));
                // equality scan, descending w-col: last write = smallest ->
                // jnp.argmax first-occurrence semantics (w-col = c*16 + q4 + j)
                int h = 0;
#pragma unroll
                for (int c = 3; c >= 0; --c)
#pragma unroll
                    for (int j = 3; j >= 0; --j)
                        h = (acc[c][rt][j] == v) ? (c * 16 + j) : h;
                h |= q4;
                // cross-q combine (4 lanes, stride 16): xor16 + xor32; tie -> smaller h
                {
                    float v2 = swz16_f(v);
                    int   h2 = swz16_i(h);
                    bool take = (v2 > v) || (v2 == v && h2 < h);
                    v = take ? v2 : v;  h = take ? h2 : h;
                    float v3 = __int_as_float(__builtin_amdgcn_ds_bpermute(a32, __float_as_int(v)));
                    int   h3 = __builtin_amdgcn_ds_bpermute(a32, h);
                    take = (v3 > v) || (v3 == v && h3 < h);
                    v = take ? v3 : v;  h = take ? h3 : h;
                }
                // running min over groups: strict < keeps first (lowest g)
                const bool better = v < ymin[rt];
                ymin[rt] = fminf(ymin[rt], v);
                code[rt] = better ? ((g << 6) | h) : code[rt];
            }
        }

        // q==0 lanes write y (contiguous 64 B per rt) and bump the histogram
        if (q == 0) {
#pragma unroll
            for (int rt = 0; rt < 2; ++rt) {
                y[base + rt * 16 + m] = ymin[rt];
                if (PRIV) atomicAdd(&lhist[code[rt]], 1u);       // LDS, banked
                else      atomicAdd(&dest[code[rt]], 1.0f);      // fallback
            }
        }
    }

    if (PRIV) {
        __syncthreads();
        // zero-skip flush; 2 blocks share a slot -> atomicAdd, but <=128
        // nonzero cells/block over 1M addresses: uncontended
        float* p = dest + (size_t)(blockIdx.x >> 1) * NCELL;
        for (int i = threadIdx.x; i < NCELL; i += 256) {
            const unsigned c = lhist[i];
            if (c) atomicAdd(&p[i], (float)c);
        }
    }
}

// Phase B: A[c] = sum over slots. 16384 atomics onto 512 cells — negligible.
__global__ void reduce_kernel(const float* __restrict__ partial, float* __restrict__ A) {
    const int tid = blockIdx.x * blockDim.x + threadIdx.x;   // 0..16383
    const int c = tid & (NCELL - 1);
    const int s = tid >> 9;                                  // 0..31
    float sum = 0.0f;
    for (int b = s; b < NSLOT; b += 32)                      // coalesced across lanes
        sum += partial[(size_t)b * NCELL + c];
    atomicAdd(&A[c], sum);
}

extern "C" void kernel_launch(void* const* d_in, const int* in_sizes, int n_in,
                              void* d_out, int out_size, void* d_ws, size_t ws_size,
                              hipStream_t stream) {
    const float* x = (const float*)d_in[0];  // [NS, NF]
    const float* z = (const float*)d_in[1];  // [KG, HKC, NF]
    const float* t = (const float*)d_in[2];  // [KG, HKC]

    float* y = (float*)d_out;        // [NS]
    float* A = (float*)d_out + NS;   // [NCELL]

    _Float16* w_hi = (_Float16*)d_ws;                          // 64 KB
    _Float16* w_lo = w_hi + (size_t)KG * HKC * NF;             // 64 KB
    float* partial = (float*)((char*)d_ws + 2 * sizeof(_Float16) * KG * HKC * NF);

    const size_t need = 2 * sizeof(_Float16) * KG * HKC * NF
                      + (size_t)NSLOT * NCELL * sizeof(float); // ~4.13 MB (known fit)

    const bool priv = (ws_size >= need);
    const int n4 = priv ? (NSLOT * NCELL / 4) : 0;

    prep_kernel<<<1024, 256, 0, stream>>>(z, w_hi, w_lo, A, (float4*)partial, n4);

    if (priv) {
        monn_mfma_kernel<true><<<NBLK, 256, 0, stream>>>(x, w_hi, w_lo, t, y, partial);
        reduce_kernel<<<64, 256, 0, stream>>>(partial, A);
    } else {
        monn_mfma_kernel<false><<<NBLK, 256, 0, stream>>>(x, w_hi, w_lo, t, y, A);
    }
}

// Round 8
// 267.043 us; speedup vs baseline: 1.9493x; 1.9493x over previous
//
#include <hip/hip_runtime.h>
#include <math.h>

// Problem constants: N=500000, NFEAT=64, K=8, HK=64
constexpr int NS    = 500000;
constexpr int NF    = 64;
constexpr int KG    = 8;
constexpr int HKC   = 64;
constexpr int NCELL = KG * HKC;            // 512 histogram cells
constexpr int RPW   = 32;                  // rows per wave (NS % 32 == 0)
constexpr int RPB   = 128;                 // rows per block (4 waves)
constexpr int NBLK  = (NS + RPB - 1) / RPB;   // 3907 (last block: 1 valid wave)
constexpr int NSLOT = 1954;                // partial slots (2 blocks share 1)
constexpr int SLICE = HKC * NF;            // 4096 halves = 8 KB per (g, hi|lo)

typedef __attribute__((ext_vector_type(8))) _Float16 half8;
typedef __attribute__((ext_vector_type(4))) float f32x4;

// xor-16 within 32-lane halves: ds_swizzle BitMode offset 0x401F
__device__ __forceinline__ float swz16_f(float v) {
    return __int_as_float(__builtin_amdgcn_ds_swizzle(__float_as_int(v), 0x401F));
}
__device__ __forceinline__ int swz16_i(int v) {
    return __builtin_amdgcn_ds_swizzle(v, 0x401F);
}

// Kernel 1: w = exp(z) split to fp16 hi/lo; zero A and the partial buffer.
__global__ void prep_kernel(const float* __restrict__ z,
                            _Float16* __restrict__ w_hi,
                            _Float16* __restrict__ w_lo,
                            float* __restrict__ A,
                            float4* __restrict__ pzero, int n4) {
    int i = blockIdx.x * blockDim.x + threadIdx.x;
    if (i < KG * HKC * NF) {
        float w = expf(z[i]);
        _Float16 h = (_Float16)w;           // RNE
        w_hi[i] = h;
        w_lo[i] = (_Float16)(w - (float)h); // residual: ~2^-22 total pair error
    }
    if (i < NCELL) A[i] = 0.0f;
    for (int j = i; j < n4; j += gridDim.x * blockDim.x)
        pzero[j] = (float4){0.f, 0.f, 0.f, 0.f};
}

// Main kernel: wave = 32 rows x 512 w-cols; per-g w slice staged block-wide
// into LDS (XOR-swizzled 16B chunks: pos = chunk ^ (row&7) -> conflict-free
// ds_read_b128, no padding). Inner loop has ZERO VMEM (R5/R6 stall source:
// 128 L2-latency B-loads/wave). __launch_bounds__(256,3): 170-reg budget,
// no spill (R7 post-mortem: (256,4)'s 128-reg cap spilled -> 343 MB scratch).
// Transposed-C mfma(W,X): lane holds 16 w-cols of ONE x-row -> in-lane argmax.
template <bool PRIV>
__global__ __launch_bounds__(256, 3) void monn_mfma_kernel(
    const float* __restrict__ x,
    const _Float16* __restrict__ w_hi,
    const _Float16* __restrict__ w_lo,
    const float* __restrict__ t,
    float* __restrict__ y,
    float* __restrict__ dest) {   // PRIV ? partial buffer : global A

    __shared__ __align__(16) char smem[2 * 8192];   // hi slice @0, lo slice @8192
    __shared__ unsigned lhist[NCELL];
    if (PRIV) {
        for (int i = threadIdx.x; i < NCELL; i += 256) lhist[i] = 0u;
    }

    const int tid  = threadIdx.x;
    const int lane = tid & 63;
    const long base  = (long)blockIdx.x * RPB + (tid >> 6) * RPW;
    const bool valid = (base < NS);
    const long cbase = valid ? base : (NS - RPW);   // clamp: loop stays uniform
    const int m  = lane & 15;
    const int q  = lane >> 4;
    const int q4 = q * 4;
    const int a32 = ((lane ^ 32) << 2);   // ds_bpermute byte-addr for xor-32
    // per-lane LDS read bases for the two k-halves (s=0,1); chunk = s*4+q
    const int x7  = m & 7;
    const int rb0 = m * 128 + (((0 + q) ^ x7) << 4);
    const int rb1 = m * 128 + (((4 + q) ^ x7) << 4);
    // staging decomposition: thread stages 32 B (2 chunks) of hi and of lo
    const int sr  = tid >> 2;              // staging row 0..63
    const int sc  = (tid & 3) * 2;         // first chunk index (0,2,4,6)
    const int sd0 = sr * 128 + (((sc)     ^ (sr & 7)) << 4);
    const int sd1 = sr * 128 + (((sc + 1) ^ (sr & 7)) << 4);

    // --- Load 32 x rows, split to fp16 hi/lo (B-operand layout:
    //     B[k=q*8+j][n=lane&15], same lane addressing as the A layout) ---
    half8 Xh[2][2], Xl[2][2];
#pragma unroll
    for (int rt = 0; rt < 2; ++rt) {
        const float* xp = x + (cbase + rt * 16 + m) * NF;
#pragma unroll
        for (int s = 0; s < 2; ++s) {
            const int k0 = s * 32 + q * 8;
            const float4 v0 = *reinterpret_cast<const float4*>(xp + k0);
            const float4 v1 = *reinterpret_cast<const float4*>(xp + k0 + 4);
            const float f[8] = {v0.x, v0.y, v0.z, v0.w, v1.x, v1.y, v1.z, v1.w};
#pragma unroll
            for (int j = 0; j < 8; ++j) {
                _Float16 h = (_Float16)f[j];
                Xh[rt][s][j] = h;
                Xl[rt][s][j] = (_Float16)(f[j] - (float)h);
            }
        }
    }

    float ymin[2] = {INFINITY, INFINITY};
    int   code[2] = {0, 0};

#pragma unroll 1
    for (int g = 0; g < KG; ++g) {
        __syncthreads();   // prior iteration's LDS reads done (also covers lhist init)
        // --- stage this group's w slice: 16 KB, coalesced, XOR-swizzled ---
        {
            const float4* sh = reinterpret_cast<const float4*>(w_hi + (size_t)g * SLICE);
            const float4* sl = reinterpret_cast<const float4*>(w_lo + (size_t)g * SLICE);
            const float4 h0 = sh[tid * 2], h1 = sh[tid * 2 + 1];
            const float4 l0 = sl[tid * 2], l1 = sl[tid * 2 + 1];
            *reinterpret_cast<float4*>(smem + sd0)        = h0;
            *reinterpret_cast<float4*>(smem + sd1)        = h1;
            *reinterpret_cast<float4*>(smem + 8192 + sd0) = l0;
            *reinterpret_cast<float4*>(smem + 8192 + sd1) = l1;
        }
        __syncthreads();

        // bias folded into acc init: lane's w-cols are c*16 + q4 + j
        f32x4 acc[4][2];   // [c (w tile)][rt (x tile)]
#pragma unroll
        for (int c = 0; c < 4; ++c) {
            const float4 tv = *reinterpret_cast<const float4*>(t + g * HKC + c * 16 + q4);
            const f32x4 tin = (f32x4){tv.x, tv.y, tv.z, tv.w};
            acc[c][0] = tin;
            acc[c][1] = tin;
        }

#pragma unroll
        for (int s = 0; s < 2; ++s) {
            const int rb = s ? rb1 : rb0;
            half8 Wh[4], Wl[4];
#pragma unroll
            for (int c = 0; c < 4; ++c) {   // ds_read_b128, immediate offsets off rb
                Wh[c] = *reinterpret_cast<const half8*>(smem + rb + c * 2048);
                Wl[c] = *reinterpret_cast<const half8*>(smem + 8192 + rb + c * 2048);
            }
            // 3 independent passes (hh, lh, hl): no dependent MFMA back-to-backs
#pragma unroll
            for (int c = 0; c < 4; ++c)
#pragma unroll
                for (int rt = 0; rt < 2; ++rt)
                    acc[c][rt] = __builtin_amdgcn_mfma_f32_16x16x32_f16(Wh[c], Xh[rt][s], acc[c][rt], 0, 0, 0);
#pragma unroll
            for (int c = 0; c < 4; ++c)
#pragma unroll
                for (int rt = 0; rt < 2; ++rt)
                    acc[c][rt] = __builtin_amdgcn_mfma_f32_16x16x32_f16(Wl[c], Xh[rt][s], acc[c][rt], 0, 0, 0);
#pragma unroll
            for (int c = 0; c < 4; ++c)
#pragma unroll
                for (int rt = 0; rt < 2; ++rt)
                    acc[c][rt] = __builtin_amdgcn_mfma_f32_16x16x32_f16(Wh[c], Xl[rt][s], acc[c][rt], 0, 0, 0);
        }

        // --- epilogue: per x-row argmax over this group's 64 w-cols ---
#pragma unroll
        for (int rt = 0; rt < 2; ++rt) {
            float t01 = fmaxf(acc[0][rt][0], acc[0][rt][1]);
            float t23 = fmaxf(acc[0][rt][2], acc[0][rt][3]);
            float t45 = fmaxf(acc[1][rt][0], acc[1][rt][1]);
            float t67 = fmaxf(acc[1][rt][2], acc[1][rt][3]);
            float t89 = fmaxf(acc[2][rt][0], acc[2][rt][1]);
            float tab = fmaxf(acc[2][rt][2], acc[2][rt][3]);
            float tcd = fmaxf(acc[3][rt][0], acc[3][rt][1]);
            float tef = fmaxf(acc[3][rt][2], acc[3][rt][3]);
            float v = fmaxf(fmaxf(fmaxf(t01, t23), fmaxf(t45, t67)),
                            fmaxf(fmaxf(t89, tab), fmaxf(tcd, tef)));
            // equality scan, descending w-col: last write = smallest ->
            // jnp.argmax first-occurrence semantics (w-col = c*16 + q4 + j)
            int h = 0;
#pragma unroll
            for (int c = 3; c >= 0; --c)
#pragma unroll
                for (int j = 3; j >= 0; --j)
                    h = (acc[c][rt][j] == v) ? (c * 16 + j) : h;
            h |= q4;
            // cross-q combine (4 lanes, stride 16): xor16 + xor32; tie -> smaller h
            {
                float v2 = swz16_f(v);
                int   h2 = swz16_i(h);
                bool take = (v2 > v) || (v2 == v && h2 < h);
                v = take ? v2 : v;  h = take ? h2 : h;
                float v3 = __int_as_float(__builtin_amdgcn_ds_bpermute(a32, __float_as_int(v)));
                int   h3 = __builtin_amdgcn_ds_bpermute(a32, h);
                take = (v3 > v) || (v3 == v && h3 < h);
                v = take ? v3 : v;  h = take ? h3 : h;
            }
            // running min over groups: strict < keeps first (lowest g)
            const bool better = v < ymin[rt];
            ymin[rt] = fminf(ymin[rt], v);
            code[rt] = better ? ((g << 6) | h) : code[rt];
        }
    }

    // q==0 lanes of VALID waves write y and bump the histogram
    if (valid && q == 0) {
#pragma unroll
        for (int rt = 0; rt < 2; ++rt) {
            y[base + rt * 16 + m] = ymin[rt];
            if (PRIV) atomicAdd(&lhist[code[rt]], 1u);       // LDS, banked
            else      atomicAdd(&dest[code[rt]], 1.0f);      // fallback
        }
    }

    if (PRIV) {
        __syncthreads();
        // zero-skip flush; 2 blocks share a slot (<=128 nonzero cells/block
        // over 1M addresses: uncontended atomics)
        float* p = dest + (size_t)(blockIdx.x >> 1) * NCELL;
        for (int i = threadIdx.x; i < NCELL; i += 256) {
            const unsigned c = lhist[i];
            if (c) atomicAdd(&p[i], (float)c);
        }
    }
}

// Phase B: A[c] = sum over slots. 16384 atomics onto 512 cells — negligible.
__global__ void reduce_kernel(const float* __restrict__ partial, float* __restrict__ A) {
    const int tid = blockIdx.x * blockDim.x + threadIdx.x;   // 0..16383
    const int c = tid & (NCELL - 1);
    const int s = tid >> 9;                                  // 0..31
    float sum = 0.0f;
    for (int b = s; b < NSLOT; b += 32)                      // coalesced across lanes
        sum += partial[(size_t)b * NCELL + c];
    atomicAdd(&A[c], sum);
}

extern "C" void kernel_launch(void* const* d_in, const int* in_sizes, int n_in,
                              void* d_out, int out_size, void* d_ws, size_t ws_size,
                              hipStream_t stream) {
    const float* x = (const float*)d_in[0];  // [NS, NF]
    const float* z = (const float*)d_in[1];  // [KG, HKC, NF]
    const float* t = (const float*)d_in[2];  // [KG, HKC]

    float* y = (float*)d_out;        // [NS]
    float* A = (float*)d_out + NS;   // [NCELL]

    _Float16* w_hi = (_Float16*)d_ws;                          // 64 KB
    _Float16* w_lo = w_hi + (size_t)KG * HKC * NF;             // 64 KB
    float* partial = (float*)((char*)d_ws + 2 * sizeof(_Float16) * KG * HKC * NF);

    const size_t need = 2 * sizeof(_Float16) * KG * HKC * NF
                      + (size_t)NSLOT * NCELL * sizeof(float); // ~4.13 MB (known fit)

    const bool priv = (ws_size >= need);
    const int n4 = priv ? (NSLOT * NCELL / 4) : 0;

    prep_kernel<<<1024, 256, 0, stream>>>(z, w_hi, w_lo, A, (float4*)partial, n4);

    if (priv) {
        monn_mfma_kernel<true><<<NBLK, 256, 0, stream>>>(x, w_hi, w_lo, t, y, partial);
        reduce_kernel<<<64, 256, 0, stream>>>(partial, A);
    } else {
        monn_mfma_kernel<false><<<NBLK, 256, 0, stream>>>(x, w_hi, w_lo, t, y, A);
    }
}